// Round 2
// baseline (100.893 us; speedup 1.0000x reference)
//
#include <hip/hip_runtime.h>

#define IMG 8
#define LH 150
#define LQ 10
#define KITER 10   // 9 scan steps + final conv (v-update on last iter is unused)

// ---------------------------------------------------------------------------
// Pre-kernel: collapse h/r convs.  r = conv(X, Weff, pad=1) + beff  where
//   Weff[t] = sum_c Wr[c] * Wh[c, t]   (t = 0..8, 3x3 tap)
//   beff    = sum_c Wr[c] * bh[c]
// ws[0..8] = Weff, ws[9] = beff.  One wave per output (10 waves).
// ---------------------------------------------------------------------------
__global__ void weff_kernel(const float* __restrict__ Wh,
                            const float* __restrict__ bh,
                            const float* __restrict__ Wr,
                            float* __restrict__ ws) {
    const int wave = threadIdx.x >> 6;   // 0..9 (wave-uniform)
    const int lane = threadIdx.x & 63;
    float partial = 0.f;
    for (int c = lane; c < LH; c += 64) {
        const float wr = Wr[c];
        partial += wr * ((wave < 9) ? Wh[c * 9 + wave] : bh[c]);
    }
    #pragma unroll
    for (int off = 32; off > 0; off >>= 1)
        partial += __shfl_xor(partial, off);   // unconditional: full wave active
    if (lane == 0) ws[wave] = partial;
}

// ---------------------------------------------------------------------------
// Main kernel: one wave per batch item, lane = pixel (y = lane>>3, x = lane&7).
// ALL shuffles execute at full-wave convergence; zero-padding is applied by a
// mask-multiply AFTER the shuffle (ds_bpermute from an exec-masked-off source
// lane returns garbage/0 — the round-1 bug).
// ---------------------------------------------------------------------------
__global__ __launch_bounds__(256) void vin_kernel(
    const float* __restrict__ S,
    const float* __restrict__ Wq,
    const float* __restrict__ w,
    const float* __restrict__ Wfc,
    const float* __restrict__ ws,
    float* __restrict__ out,
    int B) {
    const int wave = threadIdx.x >> 6;
    const int lane = threadIdx.x & 63;
    const int b = blockIdx.x * 4 + wave;
    if (b >= B) return;                       // wave-uniform

    const int y = lane >> 3, x = lane & 7;

    const float* Sb = S + (long)b * (IMG * IMG + 2);
    const float X = Sb[lane];                 // grid value for this pixel
    const int s1 = (int)Sb[IMG * IMG];
    const int s2 = (int)Sb[IMG * IMG + 1];
    const int sel_lane = s1 * 8 + s2;         // wave-uniform in practice

    // 3x3 neighbor lane indices + zero-pad masks (cross-correlation taps).
    int   nidx[9];
    float nmsk[9];
    #pragma unroll
    for (int t = 0; t < 9; ++t) {
        const int dy = t / 3 - 1, dx = t % 3 - 1;
        const int ny = y + dy, nx = x + dx;
        const bool v = ((unsigned)ny < 8u) && ((unsigned)nx < 8u);
        nidx[t] = v ? (ny * 8 + nx) : 0;
        nmsk[t] = v ? 1.f : 0.f;
    }

    // r = conv(X, Weff, pad=1) + beff   (collapsed h->r, exact)
    float Weff[9];
    #pragma unroll
    for (int t = 0; t < 9; ++t) Weff[t] = ws[t];
    const float beff = ws[9];

    float r = beff;
    #pragma unroll
    for (int t = 0; t < 9; ++t) {
        const float xv = __shfl(X, nidx[t]) * nmsk[t];   // shuffle at full convergence
        r = fmaf(Weff[t], xv, r);
    }

    // qr[o] = conv(r, Wq, pad=1)   (loop-invariant part of the value iteration)
    float rn[9];
    #pragma unroll
    for (int t = 0; t < 9; ++t)
        rn[t] = __shfl(r, nidx[t]) * nmsk[t];

    float qr[LQ];
    #pragma unroll
    for (int o = 0; o < LQ; ++o) {
        float acc = 0.f;
        #pragma unroll
        for (int t = 0; t < 9; ++t) acc = fmaf(rn[t], Wq[o * 9 + t], acc);
        qr[o] = acc;
    }

    // w into registers (wave-uniform scalar loads)
    float ww[LQ][9];
    #pragma unroll
    for (int o = 0; o < LQ; ++o)
        #pragma unroll
        for (int t = 0; t < 9; ++t) ww[o][t] = w[o * 9 + t];

    // v0 = max_o qr[o]
    float v = qr[0];
    #pragma unroll
    for (int o = 1; o < LQ; ++o) v = fmaxf(v, qr[o]);

    // Value iteration: 9 v-updates + final conv (q[] from the last iteration).
    float q[LQ];
    for (int k = 0; k < KITER; ++k) {
        float vn[9];
        #pragma unroll
        for (int t = 0; t < 9; ++t)
            vn[t] = __shfl(v, nidx[t]) * nmsk[t];        // full convergence
        float m = -3.0e38f;
        #pragma unroll
        for (int o = 0; o < LQ; ++o) {
            float acc = qr[o];
            #pragma unroll
            for (int t = 0; t < 9; ++t) acc = fmaf(vn[t], ww[o][t], acc);
            q[o] = acc;
            m = fmaxf(m, acc);
        }
        v = m;   // unused after last iteration (harmless)
    }

    // q_sel broadcast from sel_lane; lanes 0..7 emit the 8 logits.
    float qsel[LQ];
    #pragma unroll
    for (int o = 0; o < LQ; ++o) qsel[o] = __shfl(q[o], sel_lane);  // before divergence

    if (lane < 8) {
        float acc = 0.f;
        #pragma unroll
        for (int o = 0; o < LQ; ++o) acc = fmaf(qsel[o], Wfc[lane * LQ + o], acc);
        out[(long)b * 8 + lane] = acc;
    }
}

extern "C" void kernel_launch(void* const* d_in, const int* in_sizes, int n_in,
                              void* d_out, int out_size, void* d_ws, size_t ws_size,
                              hipStream_t stream) {
    const float* S   = (const float*)d_in[0];
    const float* Wh  = (const float*)d_in[1];
    const float* bh  = (const float*)d_in[2];
    const float* Wr  = (const float*)d_in[3];
    const float* Wq  = (const float*)d_in[4];
    const float* w   = (const float*)d_in[5];
    const float* Wfc = (const float*)d_in[6];
    float* out = (float*)d_out;
    float* ws  = (float*)d_ws;

    const int B = in_sizes[0] / (IMG * IMG + 2);

    weff_kernel<<<1, 640, 0, stream>>>(Wh, bh, Wr, ws);

    const int waves_per_block = 4;  // 256 threads
    const int grid = (B + waves_per_block - 1) / waves_per_block;
    vin_kernel<<<grid, 256, 0, stream>>>(S, Wq, w, Wfc, ws, out, B);
}